// Round 2
// baseline (847.602 us; speedup 1.0000x reference)
//
#include <hip/hip_runtime.h>
#include <math.h>

#define N_LEVELS 16
#define NPTS (1 << 21)

typedef float vfloat4 __attribute__((ext_vector_type(4)));

struct LevelP {
    float scale;       // (float)(res - 1)
    int   res;
    int   off;         // row offset into (TOTAL, 2) table
    unsigned int mask; // hsize-1 when hashed (hsize is always 2^19 here)
    int   is_hash;
};
struct LevelTable { LevelP lv[N_LEVELS]; };

__global__ __launch_bounds__(256) void hashenc_kernel(
        const float2* __restrict__ xy,
        const float*  __restrict__ table,
        float4* __restrict__ out,
        LevelTable lt)
{
    int tid  = blockIdx.x * 256 + threadIdx.x;
    int pair = tid & 7;      // levels 2*pair, 2*pair+1
    int p    = tid >> 3;     // point index

    float2 pt = xy[p];
    float4 o;

    #pragma unroll
    for (int k = 0; k < 2; ++k) {
        const LevelP lp = lt.lv[2 * pair + k];

        // pos = xy * (res-1) + 0.5  -- MUST be unfused mul+add to match JAX f32
        float px = __fadd_rn(__fmul_rn(pt.x, lp.scale), 0.5f);
        float py = __fadd_rn(__fmul_rn(pt.y, lp.scale), 0.5f);
        float fx = floorf(px), fy = floorf(py);
        float wx = __fsub_rn(px, fx), wy = __fsub_rn(py, fy);
        int gx = (int)fx, gy = (int)fy;

        int i00, i10, i01, i11;
        if (lp.is_hash) {
            const unsigned K1 = 2654435761u;
            unsigned ux = (unsigned)gx, uy = (unsigned)gy;
            unsigned hy0 = uy * K1, hy1 = (uy + 1u) * K1;
            i00 = (int)((ux        ^ hy0) & lp.mask);
            i10 = (int)(((ux + 1u) ^ hy0) & lp.mask);
            i01 = (int)((ux        ^ hy1) & lp.mask);
            i11 = (int)(((ux + 1u) ^ hy1) & lp.mask);
        } else {
            i00 = gx + gy * lp.res;
            i10 = i00 + 1;
            i01 = i00 + lp.res;
            i11 = i01 + 1;
        }

        const float2* tb = (const float2*)table + lp.off;
        float2 f00 = tb[i00];
        float2 f10 = tb[i10];
        float2 f01 = tb[i01];
        float2 f11 = tb[i11];

        float owx = 1.0f - wx, owy = 1.0f - wy;
        float w00 = owx * owy, w10 = wx * owy, w01 = owx * wy, w11 = wx * wy;
        float ox = f00.x * w00 + f10.x * w10 + f01.x * w01 + f11.x * w11;
        float oy = f00.y * w00 + f10.y * w10 + f01.y * w01 + f11.y * w11;

        if (k == 0) { o.x = ox; o.y = oy; }
        else        { o.z = ox; o.w = oy; }
    }

    // 64 lanes -> 64 consecutive float4 = 1 KiB contiguous, non-temporal
    // (don't let the 256 MiB output stream evict the 29 MiB table from L2/L3).
    // Cast through a native clang vector type: the builtin rejects HIP_vector_type.
    vfloat4 ov = { o.x, o.y, o.z, o.w };
    __builtin_nontemporal_store(ov, (vfloat4*)&out[(size_t)p * 8 + pair]);
}

extern "C" void kernel_launch(void* const* d_in, const int* in_sizes, int n_in,
                              void* d_out, int out_size, void* d_ws, size_t ws_size,
                              hipStream_t stream) {
    const float2* xy     = (const float2*)d_in[0];
    const float*  params = (const float*)d_in[1];
    float4*       out    = (float4*)d_out;

    // Recompute level geometry with the SAME libm as the reference's Python
    // (same process, same glibc) -- avoids off-by-one at exact-integer scales.
    LevelTable lt;
    double log2s = log2(1.5);
    long offs[N_LEVELS];
    int  res_arr[N_LEVELS];
    long off = 0;
    for (int l = 0; l < N_LEVELS; ++l) {
        double scale = pow(2.0, (double)l * log2s) * 16.0 - 1.0;
        int r = (int)ceil(scale) + 1;
        res_arr[l] = r;
        offs[l] = off;
        long sz = ((long)r * r + 7) / 8 * 8;
        if (sz > (1L << 19)) sz = 1L << 19;
        off += sz;
    }
    for (int l = 0; l < N_LEVELS; ++l) {
        long hsize = ((l + 1 < N_LEVELS) ? offs[l + 1] : off) - offs[l];
        long r2 = (long)res_arr[l] * res_arr[l];
        int is_hash = hsize < r2;
        lt.lv[l].scale   = (float)(res_arr[l] - 1);
        lt.lv[l].res     = res_arr[l];
        lt.lv[l].off     = (int)offs[l];
        lt.lv[l].is_hash = is_hash;
        lt.lv[l].mask    = is_hash ? (unsigned)(hsize - 1) : 0u;
    }

    long total_threads = (long)NPTS * 8;           // one thread per (point, level-pair)
    dim3 grid((unsigned)(total_threads / 256)), block(256);
    hipLaunchKernelGGL(hashenc_kernel, grid, block, 0, stream,
                       xy, params, out, lt);
}

// Round 3
// 771.742 us; speedup vs baseline: 1.0983x; 1.0983x over previous
//
#include <hip/hip_runtime.h>
#include <math.h>

#define N_LEVELS 16
#define NPTS (1 << 21)

typedef float vfloat4 __attribute__((ext_vector_type(4)));
typedef float vfloat2 __attribute__((ext_vector_type(2)));

struct LevelP {
    float scale;       // (float)(res - 1)
    int   res;
    int   off;         // row offset into (TOTAL, 2) table
    unsigned int mask; // hsize-1 when hashed (hsize is 2^19 here)
    int   is_hash;
};
struct LevelTable { LevelP lv[N_LEVELS]; };
struct LevelMap   { int m[8][2]; };   // [xcd][phase] -> level

// ---------------------------------------------------------------------------
// Kernel A: level-partitioned encode.  One block = one level x 2048 points.
// blockIdx&7 ~ XCD id (hardware round-robins consecutive blockIdx across the
// 8 XCDs); hashed levels (4 MiB table each) are pinned one-per-XCD so the
// random gathers hit an L2-resident table instead of thrashing to HBM.
// Writes level-major float2 planes into ws (coalesced, non-temporal).
// ---------------------------------------------------------------------------
__global__ __launch_bounds__(256) void enc_level_kernel(
        const float2* __restrict__ xy,
        const float*  __restrict__ table,
        float2* __restrict__ ws,
        LevelTable lt, LevelMap lm)
{
    int xcd   = blockIdx.x & 7;
    int slot  = blockIdx.x >> 3;        // 0..2047 per xcd
    int lvl   = lm.m[xcd][slot >> 10];  // phase 0: slots 0..1023, phase 1: rest
    int chunk = slot & 1023;            // 1024 chunks x 2048 pts = 2^21

    const LevelP lp = lt.lv[lvl];
    const float2* tb = (const float2*)table + lp.off;
    float2* wsl = ws + (size_t)lvl * NPTS;

    int base = chunk * 2048 + threadIdx.x;

    #pragma unroll
    for (int i = 0; i < 8; ++i) {
        int p = base + i * 256;
        float2 pt = xy[p];

        // pos = xy*(res-1)+0.5 -- unfused mul+add to match JAX f32 exactly
        float px = __fadd_rn(__fmul_rn(pt.x, lp.scale), 0.5f);
        float py = __fadd_rn(__fmul_rn(pt.y, lp.scale), 0.5f);
        float fx = floorf(px), fy = floorf(py);
        float wx = __fsub_rn(px, fx), wy = __fsub_rn(py, fy);
        int gx = (int)fx, gy = (int)fy;

        int i00, i10, i01, i11;
        if (lp.is_hash) {
            const unsigned K1 = 2654435761u;
            unsigned ux = (unsigned)gx, uy = (unsigned)gy;
            unsigned hy0 = uy * K1, hy1 = (uy + 1u) * K1;
            i00 = (int)((ux        ^ hy0) & lp.mask);
            i10 = (int)(((ux + 1u) ^ hy0) & lp.mask);
            i01 = (int)((ux        ^ hy1) & lp.mask);
            i11 = (int)(((ux + 1u) ^ hy1) & lp.mask);
        } else {
            i00 = gx + gy * lp.res;
            i10 = i00 + 1;
            i01 = i00 + lp.res;
            i11 = i01 + 1;
        }

        float2 f00 = tb[i00];
        float2 f10 = tb[i10];
        float2 f01 = tb[i01];
        float2 f11 = tb[i11];

        float owx = 1.0f - wx, owy = 1.0f - wy;
        float w00 = owx * owy, w10 = wx * owy, w01 = owx * wy, w11 = wx * wy;
        vfloat2 o;
        o.x = f00.x * w00 + f10.x * w10 + f01.x * w01 + f11.x * w11;
        o.y = f00.y * w00 + f10.y * w10 + f01.y * w01 + f11.y * w11;

        __builtin_nontemporal_store(o, (vfloat2*)&wsl[p]);
    }
}

// ---------------------------------------------------------------------------
// Kernel B: interleave ws planes -> out (N, 16*2).  Pure streaming.
// thread = (point, level-pair): two coalesced 8B plane loads, one 16B nt store.
// ---------------------------------------------------------------------------
__global__ __launch_bounds__(256) void interleave_kernel(
        const float2* __restrict__ ws,
        float4* __restrict__ out)
{
    int tid  = blockIdx.x * 256 + threadIdx.x;
    int pair = tid & 7;
    int p    = tid >> 3;

    const vfloat2* a = (const vfloat2*)(ws + (size_t)(2 * pair)     * NPTS);
    const vfloat2* b = (const vfloat2*)(ws + (size_t)(2 * pair + 1) * NPTS);
    vfloat2 va = __builtin_nontemporal_load(&a[p]);
    vfloat2 vb = __builtin_nontemporal_load(&b[p]);

    vfloat4 o = { va.x, va.y, vb.x, vb.y };
    __builtin_nontemporal_store(o, (vfloat4*)&out[(size_t)p * 8 + pair]);
}

// ---------------------------------------------------------------------------
// Fallback single-kernel (round-2 version) for when ws is too small.
// ---------------------------------------------------------------------------
__global__ __launch_bounds__(256) void hashenc_kernel(
        const float2* __restrict__ xy,
        const float*  __restrict__ table,
        float4* __restrict__ out,
        LevelTable lt)
{
    int tid  = blockIdx.x * 256 + threadIdx.x;
    int pair = tid & 7;
    int p    = tid >> 3;

    float2 pt = xy[p];
    float4 o;

    #pragma unroll
    for (int k = 0; k < 2; ++k) {
        const LevelP lp = lt.lv[2 * pair + k];
        float px = __fadd_rn(__fmul_rn(pt.x, lp.scale), 0.5f);
        float py = __fadd_rn(__fmul_rn(pt.y, lp.scale), 0.5f);
        float fx = floorf(px), fy = floorf(py);
        float wx = __fsub_rn(px, fx), wy = __fsub_rn(py, fy);
        int gx = (int)fx, gy = (int)fy;

        int i00, i10, i01, i11;
        if (lp.is_hash) {
            const unsigned K1 = 2654435761u;
            unsigned ux = (unsigned)gx, uy = (unsigned)gy;
            unsigned hy0 = uy * K1, hy1 = (uy + 1u) * K1;
            i00 = (int)((ux        ^ hy0) & lp.mask);
            i10 = (int)(((ux + 1u) ^ hy0) & lp.mask);
            i01 = (int)((ux        ^ hy1) & lp.mask);
            i11 = (int)(((ux + 1u) ^ hy1) & lp.mask);
        } else {
            i00 = gx + gy * lp.res;
            i10 = i00 + 1;
            i01 = i00 + lp.res;
            i11 = i01 + 1;
        }

        const float2* tb = (const float2*)table + lp.off;
        float2 f00 = tb[i00];
        float2 f10 = tb[i10];
        float2 f01 = tb[i01];
        float2 f11 = tb[i11];

        float owx = 1.0f - wx, owy = 1.0f - wy;
        float w00 = owx * owy, w10 = wx * owy, w01 = owx * wy, w11 = wx * wy;
        float ox = f00.x * w00 + f10.x * w10 + f01.x * w01 + f11.x * w11;
        float oy = f00.y * w00 + f10.y * w10 + f01.y * w01 + f11.y * w11;

        if (k == 0) { o.x = ox; o.y = oy; }
        else        { o.z = ox; o.w = oy; }
    }

    vfloat4 ov = { o.x, o.y, o.z, o.w };
    __builtin_nontemporal_store(ov, (vfloat4*)&out[(size_t)p * 8 + pair]);
}

extern "C" void kernel_launch(void* const* d_in, const int* in_sizes, int n_in,
                              void* d_out, int out_size, void* d_ws, size_t ws_size,
                              hipStream_t stream) {
    const float2* xy     = (const float2*)d_in[0];
    const float*  params = (const float*)d_in[1];
    float4*       out    = (float4*)d_out;

    // Level geometry with the same libm as the reference's Python process.
    LevelTable lt;
    double log2s = log2(1.5);
    long offs[N_LEVELS];
    int  res_arr[N_LEVELS];
    long off = 0;
    for (int l = 0; l < N_LEVELS; ++l) {
        double scale = pow(2.0, (double)l * log2s) * 16.0 - 1.0;
        int r = (int)ceil(scale) + 1;
        res_arr[l] = r;
        offs[l] = off;
        long sz = ((long)r * r + 7) / 8 * 8;
        if (sz > (1L << 19)) sz = 1L << 19;
        off += sz;
    }
    for (int l = 0; l < N_LEVELS; ++l) {
        long hsize = ((l + 1 < N_LEVELS) ? offs[l + 1] : off) - offs[l];
        long r2 = (long)res_arr[l] * res_arr[l];
        int is_hash = hsize < r2;
        lt.lv[l].scale   = (float)(res_arr[l] - 1);
        lt.lv[l].res     = res_arr[l];
        lt.lv[l].off     = (int)offs[l];
        lt.lv[l].is_hash = is_hash;
        lt.lv[l].mask    = is_hash ? (unsigned)(hsize - 1) : 0u;
    }

    size_t ws_needed = (size_t)N_LEVELS * NPTS * 2 * sizeof(float); // 256 MiB
    if (ws_size >= ws_needed) {
        // Hashed levels 10..15 (4 MiB tables) pinned one per XCD 0..5;
        // dense levels fill the remaining slots, 2 levels per XCD (balanced).
        LevelMap lm;
        int map[8][2] = { {10,0},{11,1},{12,2},{13,3},{14,4},{15,5},{6,7},{8,9} };
        for (int x = 0; x < 8; ++x) { lm.m[x][0] = map[x][0]; lm.m[x][1] = map[x][1]; }

        float2* ws = (float2*)d_ws;
        dim3 gridA(16384), block(256);             // 8 xcd * 2 phases * 1024 chunks
        hipLaunchKernelGGL(enc_level_kernel, gridA, block, 0, stream,
                           xy, params, ws, lt, lm);
        dim3 gridB((NPTS * 8) / 256);
        hipLaunchKernelGGL(interleave_kernel, gridB, block, 0, stream,
                           (const float2*)ws, out);
    } else {
        long total_threads = (long)NPTS * 8;
        dim3 grid((unsigned)(total_threads / 256)), block(256);
        hipLaunchKernelGGL(hashenc_kernel, grid, block, 0, stream,
                           xy, params, out, lt);
    }
}

// Round 4
// 698.266 us; speedup vs baseline: 1.2139x; 1.1052x over previous
//
#include <hip/hip_runtime.h>
#include <math.h>

#define N_LEVELS 16
#define NPTS (1 << 21)

typedef float vfloat4 __attribute__((ext_vector_type(4)));
typedef float vfloat2 __attribute__((ext_vector_type(2)));

struct LevelP {
    float scale;       // (float)(res - 1)
    int   res;
    int   off;         // row offset into (TOTAL, 2) table
    unsigned int mask; // hsize-1 when hashed (hsize is 2^19 here)
    int   is_hash;
};
struct LevelTable { LevelP lv[N_LEVELS]; };
struct LevelMap   { int m[8][2]; };   // [xcd][phase] -> level

// ---------------------------------------------------------------------------
// Kernel A: level-partitioned encode, MLP-batched.
// One block = one level x 2048 points. blockIdx&7 ~ XCD id; hashed levels
// (4 MiB tables) pinned one-per-XCD so gathers hit an L2-resident table.
// Batch of 4 points: compute all 16 corner indices, issue all 16 gathers,
// THEN consume -- keeps ~16 loads in flight per wave (round-3 had VGPR=16
// and only ~4 outstanding -> latency-bound at 0.5 req/cyc/CU).
// ---------------------------------------------------------------------------
__global__ __launch_bounds__(256) void enc_level_kernel(
        const float2* __restrict__ xy,
        const float*  __restrict__ table,
        float2* __restrict__ ws,
        LevelTable lt, LevelMap lm)
{
    int xcd   = blockIdx.x & 7;
    int slot  = blockIdx.x >> 3;        // 0..2047 per xcd
    int lvl   = lm.m[xcd][slot >> 10];  // phase 0: slots 0..1023, phase 1: rest
    int chunk = slot & 1023;            // 1024 chunks x 2048 pts = 2^21

    const LevelP lp = lt.lv[lvl];
    const float2* tb = (const float2*)table + lp.off;
    float2* wsl = ws + (size_t)lvl * NPTS;

    int base = chunk * 2048 + threadIdx.x;

    #pragma unroll
    for (int half = 0; half < 2; ++half) {

        // ---- gather-address phase (4 points x 4 corners) ----
        float wxs[4], wys[4];
        int   idx[4][4];
        #pragma unroll
        for (int i = 0; i < 4; ++i) {
            int p = base + half * 1024 + i * 256;
            float2 pt = xy[p];

            // pos = xy*(res-1)+0.5 -- unfused mul+add to match JAX f32
            float px = __fadd_rn(__fmul_rn(pt.x, lp.scale), 0.5f);
            float py = __fadd_rn(__fmul_rn(pt.y, lp.scale), 0.5f);
            float fx = floorf(px), fy = floorf(py);
            wxs[i] = __fsub_rn(px, fx);
            wys[i] = __fsub_rn(py, fy);
            int gx = (int)fx, gy = (int)fy;

            if (lp.is_hash) {
                const unsigned K1 = 2654435761u;
                unsigned ux = (unsigned)gx, uy = (unsigned)gy;
                unsigned hy0 = uy * K1, hy1 = (uy + 1u) * K1;
                idx[i][0] = (int)((ux        ^ hy0) & lp.mask);
                idx[i][1] = (int)(((ux + 1u) ^ hy0) & lp.mask);
                idx[i][2] = (int)((ux        ^ hy1) & lp.mask);
                idx[i][3] = (int)(((ux + 1u) ^ hy1) & lp.mask);
            } else {
                int i00 = gx + gy * lp.res;
                idx[i][0] = i00;
                idx[i][1] = i00 + 1;
                idx[i][2] = i00 + lp.res;
                idx[i][3] = i00 + lp.res + 1;
            }
        }

        // ---- issue all 16 gathers (independent, stay in flight) ----
        float2 f[4][4];
        #pragma unroll
        for (int i = 0; i < 4; ++i)
            #pragma unroll
            for (int c = 0; c < 4; ++c)
                f[i][c] = tb[idx[i][c]];

        // ---- consume + store ----
        #pragma unroll
        for (int i = 0; i < 4; ++i) {
            float wx = wxs[i], wy = wys[i];
            float owx = 1.0f - wx, owy = 1.0f - wy;
            float w00 = owx * owy, w10 = wx * owy, w01 = owx * wy, w11 = wx * wy;
            vfloat2 o;
            o.x = f[i][0].x * w00 + f[i][1].x * w10 + f[i][2].x * w01 + f[i][3].x * w11;
            o.y = f[i][0].y * w00 + f[i][1].y * w10 + f[i][2].y * w01 + f[i][3].y * w11;
            int p = base + half * 1024 + i * 256;
            __builtin_nontemporal_store(o, (vfloat2*)&wsl[p]);
        }
    }
}

// ---------------------------------------------------------------------------
// Kernel B: interleave ws planes -> out (N, 32) via LDS transpose.
// Block = 256 points. Phase 1: 16 coalesced 8B/lane plane loads -> LDS
// (row stride 258 float2 -> only 2-way bank aliasing = free).
// Phase 2: fully contiguous float4 stores (1 KiB/wave).
// ---------------------------------------------------------------------------
#define ROWP 258
__global__ __launch_bounds__(256) void interleave_kernel(
        const float2* __restrict__ ws,
        float4* __restrict__ out)
{
    __shared__ float2 lds[N_LEVELS * ROWP];

    int t = threadIdx.x;
    int pbase = blockIdx.x * 256;

    #pragma unroll
    for (int l = 0; l < N_LEVELS; ++l) {
        vfloat2 v = __builtin_nontemporal_load(
            (const vfloat2*)&ws[(size_t)l * NPTS + pbase + t]);
        lds[l * ROWP + t] = float2{ v.x, v.y };
    }
    __syncthreads();

    #pragma unroll
    for (int w = 0; w < 8; ++w) {
        int s = w * 256 + t;          // 0..2047 output float4 within block
        int p = s >> 3, k = s & 7;
        float2 a = lds[(2 * k)     * ROWP + p];
        float2 b = lds[(2 * k + 1) * ROWP + p];
        vfloat4 o = { a.x, a.y, b.x, b.y };
        __builtin_nontemporal_store(o, (vfloat4*)&out[(size_t)pbase * 8 + s]);
    }
}

// ---------------------------------------------------------------------------
// Fallback single-kernel for when ws is too small.
// ---------------------------------------------------------------------------
__global__ __launch_bounds__(256) void hashenc_kernel(
        const float2* __restrict__ xy,
        const float*  __restrict__ table,
        float4* __restrict__ out,
        LevelTable lt)
{
    int tid  = blockIdx.x * 256 + threadIdx.x;
    int pair = tid & 7;
    int p    = tid >> 3;

    float2 pt = xy[p];
    float4 o;

    #pragma unroll
    for (int k = 0; k < 2; ++k) {
        const LevelP lp = lt.lv[2 * pair + k];
        float px = __fadd_rn(__fmul_rn(pt.x, lp.scale), 0.5f);
        float py = __fadd_rn(__fmul_rn(pt.y, lp.scale), 0.5f);
        float fx = floorf(px), fy = floorf(py);
        float wx = __fsub_rn(px, fx), wy = __fsub_rn(py, fy);
        int gx = (int)fx, gy = (int)fy;

        int i00, i10, i01, i11;
        if (lp.is_hash) {
            const unsigned K1 = 2654435761u;
            unsigned ux = (unsigned)gx, uy = (unsigned)gy;
            unsigned hy0 = uy * K1, hy1 = (uy + 1u) * K1;
            i00 = (int)((ux        ^ hy0) & lp.mask);
            i10 = (int)(((ux + 1u) ^ hy0) & lp.mask);
            i01 = (int)((ux        ^ hy1) & lp.mask);
            i11 = (int)(((ux + 1u) ^ hy1) & lp.mask);
        } else {
            i00 = gx + gy * lp.res;
            i10 = i00 + 1;
            i01 = i00 + lp.res;
            i11 = i01 + 1;
        }

        const float2* tb = (const float2*)table + lp.off;
        float2 f00 = tb[i00];
        float2 f10 = tb[i10];
        float2 f01 = tb[i01];
        float2 f11 = tb[i11];

        float owx = 1.0f - wx, owy = 1.0f - wy;
        float w00 = owx * owy, w10 = wx * owy, w01 = owx * wy, w11 = wx * wy;
        float ox = f00.x * w00 + f10.x * w10 + f01.x * w01 + f11.x * w11;
        float oy = f00.y * w00 + f10.y * w10 + f01.y * w01 + f11.y * w11;

        if (k == 0) { o.x = ox; o.y = oy; }
        else        { o.z = ox; o.w = oy; }
    }

    vfloat4 ov = { o.x, o.y, o.z, o.w };
    __builtin_nontemporal_store(ov, (vfloat4*)&out[(size_t)p * 8 + pair]);
}

extern "C" void kernel_launch(void* const* d_in, const int* in_sizes, int n_in,
                              void* d_out, int out_size, void* d_ws, size_t ws_size,
                              hipStream_t stream) {
    const float2* xy     = (const float2*)d_in[0];
    const float*  params = (const float*)d_in[1];
    float4*       out    = (float4*)d_out;

    // Level geometry with the same libm as the reference's Python process.
    LevelTable lt;
    double log2s = log2(1.5);
    long offs[N_LEVELS];
    int  res_arr[N_LEVELS];
    long off = 0;
    for (int l = 0; l < N_LEVELS; ++l) {
        double scale = pow(2.0, (double)l * log2s) * 16.0 - 1.0;
        int r = (int)ceil(scale) + 1;
        res_arr[l] = r;
        offs[l] = off;
        long sz = ((long)r * r + 7) / 8 * 8;
        if (sz > (1L << 19)) sz = 1L << 19;
        off += sz;
    }
    for (int l = 0; l < N_LEVELS; ++l) {
        long hsize = ((l + 1 < N_LEVELS) ? offs[l + 1] : off) - offs[l];
        long r2 = (long)res_arr[l] * res_arr[l];
        int is_hash = hsize < r2;
        lt.lv[l].scale   = (float)(res_arr[l] - 1);
        lt.lv[l].res     = res_arr[l];
        lt.lv[l].off     = (int)offs[l];
        lt.lv[l].is_hash = is_hash;
        lt.lv[l].mask    = is_hash ? (unsigned)(hsize - 1) : 0u;
    }

    size_t ws_needed = (size_t)N_LEVELS * NPTS * 2 * sizeof(float); // 256 MiB
    if (ws_size >= ws_needed) {
        // Hashed levels 10..15 (4 MiB tables) pinned one per XCD 0..5;
        // dense levels fill the remaining slots, 2 levels per XCD (balanced).
        LevelMap lm;
        int map[8][2] = { {10,0},{11,1},{12,2},{13,3},{14,4},{15,5},{6,7},{8,9} };
        for (int x = 0; x < 8; ++x) { lm.m[x][0] = map[x][0]; lm.m[x][1] = map[x][1]; }

        float2* ws = (float2*)d_ws;
        dim3 gridA(16384), block(256);             // 8 xcd * 2 phases * 1024 chunks
        hipLaunchKernelGGL(enc_level_kernel, gridA, block, 0, stream,
                           xy, params, ws, lt, lm);
        dim3 gridB(NPTS / 256);
        hipLaunchKernelGGL(interleave_kernel, gridB, block, 0, stream,
                           (const float2*)ws, out);
    } else {
        long total_threads = (long)NPTS * 8;
        dim3 grid((unsigned)(total_threads / 256)), block(256);
        hipLaunchKernelGGL(hashenc_kernel, grid, block, 0, stream,
                           xy, params, out, lt);
    }
}